// Round 15
// baseline (1399.980 us; speedup 1.0000x reference)
//
#include <hip/hip_runtime.h>

#define NTT 256
#define NCC 128

typedef __attribute__((ext_vector_type(8))) short bf16x8;
typedef __attribute__((ext_vector_type(4))) float f32x4;

__device__ __forceinline__ float dfh_tanh_f(float v){ return tanhf(v)*0.98f + 0.02f*v; }
__device__ __forceinline__ float dfh_sig_f(float v){ return 0.98f/(1.f+expf(-v)) + 0.02f*v; }
__device__ __forceinline__ unsigned f2bf(float x){
  unsigned u = __float_as_uint(x);
  return (u + 0x7fffu + ((u>>16)&1u)) >> 16;
}

// ---------------- build c-layer input + dense + tanh; zero skip -------------
__global__ __launch_bounds__(256) void k_build_c(
    const float* __restrict__ times, const float* __restrict__ times_in,
    const float* __restrict__ i2nc, const float* __restrict__ i2c,
    const float* __restrict__ dw, const float* __restrict__ db,
    float* __restrict__ x, unsigned short* __restrict__ xb,
    float* __restrict__ skip)
{
  int gid = blockIdx.x*256 + threadIdx.x;          // t*128 + c
  if (gid >= NTT*NCC) return;
  int c = gid & 127, t = gid >> 7;
  float v0 = i2nc[c*NTT + t];
  float v1 = i2c [c*NTT + t];
  float v2 = times[t];
  float v3 = times_in[c];
  #pragma unroll
  for (int f=0; f<16; ++f){
    float a = v0*dw[f] + v1*dw[16+f] + v2*dw[32+f] + v3*dw[48+f] + db[f];
    float xv = dfh_tanh_f(a);
    x[gid*16+f]    = xv;
    xb[gid*16+f]   = (unsigned short)f2bf(xv);
    skip[gid*16+f] = 0.f;
  }
}

// ---------------- h-layer dense + tanh; zero skip ---------------------------
__global__ __launch_bounds__(256) void k_build_h(
    const float* __restrict__ hinp, const float* __restrict__ dw,
    const float* __restrict__ db, float* __restrict__ x,
    unsigned short* __restrict__ xb, float* __restrict__ skip)
{
  int gid = blockIdx.x*256 + threadIdx.x;          // c*256 + t
  if (gid >= NCC*NTT) return;
  const float* in = hinp + gid*16;
  float iv[16];
  #pragma unroll
  for (int i=0;i<16;i++) iv[i]=in[i];
  #pragma unroll
  for (int f=0; f<16; ++f){
    float a = db[f];
    #pragma unroll
    for (int i=0;i<16;i++) a += iv[i]*dw[i*16+f];
    float xv = dfh_tanh_f(a);
    x[gid*16+f]    = xv;
    xb[gid*16+f]   = (unsigned short)f2bf(xv);
    skip[gid*16+f] = 0.f;
  }
}

// ---------------- pack wave-layer weights into MFMA fragment order ----------
__global__ __launch_bounds__(256) void k_wpack(
    const float* __restrict__ cwy1, const float* __restrict__ cwy2,
    const float* __restrict__ cwz0,
    const float* __restrict__ hwy1, const float* __restrict__ hwy2,
    const float* __restrict__ hwz0,
    unsigned short* __restrict__ gfrag, unsigned short* __restrict__ zfrag)
{
  int tid = blockIdx.x*256 + threadIdx.x;
  if (tid < 115200){
    int lane = tid & 63, ks = (tid>>6) % 20, layer = tid / 1280;
    const float* w1 = (layer < 45) ? cwy1 + layer*5120 : hwy1 + (layer-45)*5120;
    const float* w2 = (layer < 45) ? cwy2 + layer*5120 : hwy2 + (layer-45)*5120;
    int n = lane & 15;
    unsigned pk[4];
    #pragma unroll
    for (int jj=0; jj<4; ++jj){
      unsigned hl[2];
      #pragma unroll
      for (int h2=0; h2<2; ++h2){
        int k = ks*32 + (lane>>4)*8 + jj*2 + h2;
        int tap = k>>4, ci = k&15;
        float v = (n<8) ? w1[(tap*16+ci)*8 + n] : w2[(tap*16+ci)*8 + (n-8)];
        hl[h2] = f2bf(v);
      }
      pk[jj] = hl[0] | (hl[1]<<16);
    }
    uint4 v4; v4.x=pk[0]; v4.y=pk[1]; v4.z=pk[2]; v4.w=pk[3];
    *reinterpret_cast<uint4*>(gfrag + (size_t)tid*8) = v4;
  } else if (tid < 172800){
    int t2 = tid - 115200;
    int lane = t2 & 63, ks = (t2>>6) % 10, layer = t2 / 640;
    const float* wz = (layer < 45) ? cwz0 + layer*5120 : hwz0 + (layer-45)*5120;
    int n = lane & 15;
    unsigned pk[4];
    #pragma unroll
    for (int jj=0; jj<4; ++jj){
      unsigned hl[2];
      #pragma unroll
      for (int h2=0; h2<2; ++h2){
        int k = ks*32 + (lane>>4)*8 + jj*2 + h2;
        int tap = k>>3, ci = k&7;
        hl[h2] = f2bf(wz[(tap*8+ci)*16 + n]);
      }
      pk[jj] = hl[0] | (hl[1]<<16);
    }
    uint4 v4; v4.x=pk[0]; v4.y=pk[1]; v4.z=pk[2]; v4.w=pk[3];
    *reinterpret_cast<uint4*>(zfrag + (size_t)t2*8) = v4;
  }
}

// ---------------- gate: g = dfh_tanh(y1)*dfh_sigmoid(y2) via MFMA -----------
// xb: [H][W][16] bf16. grid = H*(W/128), 512 threads. M=128 per block, N=16.
// XCD-chunked row swizzle; B-frags preloaded to regs; dual-accumulator ILP.
template<int W>
__global__ __launch_bounds__(512) void k_gate_mfma(
    const unsigned short* __restrict__ xb, unsigned short* __restrict__ gb,
    const unsigned short* __restrict__ bfrag,
    const float* __restrict__ by1, const float* __restrict__ by2,
    int H, int dil)
{
  __shared__ __align__(16) unsigned short lds[(10*W+1)*8];
  const int tid = threadIdx.x, lane = tid & 63, wv = tid >> 6;
  const int nb = W/128;
  const int bid = blockIdx.x;
  const int wg = (bid & 7) * (gridDim.x >> 3) + (bid >> 3);  // XCD-chunked
  const int h  = wg / nb;
  const int w0 = (wg % nb) * 128;
  const int NE = 10*W;

  bf16x8 bfr[20];                                  // preload B-frags (T14)
  #pragma unroll
  for (int ks = 0; ks < 20; ++ks)
    bfr[ks] = *reinterpret_cast<const bf16x8*>(bfrag + (ks*64 + lane)*8);

  for (int q = tid; q < NE; q += 512){
    int q2 = q >> 1, chunk = q & 1;
    int col = q2 % W, r = q2 / W;
    int hh = h + r - 2;
    uint4 v = make_uint4(0u,0u,0u,0u);
    if (hh >= 0 && hh < H)
      v = *reinterpret_cast<const uint4*>(xb + ((size_t)(hh*W+col))*16 + chunk*8);
    *reinterpret_cast<uint4*>(lds + ((r*2+chunk)*W + col)*8) = v;
  }
  if (tid == 0) *reinterpret_cast<uint4*>(lds + (size_t)NE*8) = make_uint4(0u,0u,0u,0u);
  __syncthreads();

  f32x4 acc0 = (f32x4){0.f,0.f,0.f,0.f};
  f32x4 acc1 = (f32x4){0.f,0.f,0.f,0.f};
  const int wbase = w0 + wv*16;
  const int zoff = NE*8;
  #pragma unroll
  for (int ks = 0; ks < 20; ++ks){
    int kh = ks >> 2, kw0 = (ks & 3)*2;
    if (w0 + dil*kw0 >= W) continue;               // uniform: all-zero step
    int kw = kw0 + (lane>>5);
    int chunk = (lane>>4) & 1;
    int col = wbase + (lane&15) + dil*kw;
    int off = (col < W) ? ((kh*2+chunk)*W + col)*8 : zoff;
    bf16x8 a = *reinterpret_cast<const bf16x8*>(lds + off);
    if (ks & 1) acc1 = __builtin_amdgcn_mfma_f32_16x16x32_bf16(a, bfr[ks], acc1, 0,0,0);
    else        acc0 = __builtin_amdgcn_mfma_f32_16x16x32_bf16(a, bfr[ks], acc0, 0,0,0);
  }

  int n = lane & 15;
  float b1 = by1[n & 7], b2 = by2[n & 7];
  #pragma unroll
  for (int ri=0; ri<4; ++ri){
    float av = acc0[ri] + acc1[ri];
    float own = av + b1;
    float oth = __shfl_xor(av, 8) + b2;
    if (n < 8){
      float gv = dfh_tanh_f(own) * dfh_sig_f(oth);
      int w = wbase + (lane>>4)*4 + ri;
      gb[((size_t)(h*W + w))*8 + n] = (unsigned short)f2bf(gv);
    }
  }
}

// ---------------- zres: z-conv via MFMA + skip/x residual + bf16 mirror -----
template<int W>
__global__ __launch_bounds__(512) void k_zres_mfma(
    const unsigned short* __restrict__ gb,
    float* __restrict__ x, unsigned short* __restrict__ xb,
    float* __restrict__ skip,
    const unsigned short* __restrict__ bfrag,
    const float* __restrict__ bz, int H)
{
  __shared__ __align__(16) unsigned short lds[(5*W+1)*8];
  const int tid = threadIdx.x, lane = tid & 63, wv = tid >> 6;
  const int nb = W/128;
  const int bid = blockIdx.x;
  const int wg = (bid & 7) * (gridDim.x >> 3) + (bid >> 3);  // XCD-chunked
  const int h  = wg / nb;
  const int w0 = (wg % nb) * 128;

  bf16x8 bfr[10];                                  // preload B-frags
  #pragma unroll
  for (int ks = 0; ks < 10; ++ks)
    bfr[ks] = *reinterpret_cast<const bf16x8*>(bfrag + (ks*64 + lane)*8);

  for (int q = tid; q < 5*W; q += 512){
    int col = q % W, r = q / W;
    int hh = h + r - 2;
    uint4 v = make_uint4(0u,0u,0u,0u);
    if (hh >= 0 && hh < H)
      v = *reinterpret_cast<const uint4*>(gb + ((size_t)(hh*W+col))*8);
    *reinterpret_cast<uint4*>(lds + (r*W+col)*8) = v;
  }
  if (tid == 0) *reinterpret_cast<uint4*>(lds + (size_t)(5*W)*8) = make_uint4(0u,0u,0u,0u);
  __syncthreads();

  f32x4 acc0 = (f32x4){0.f,0.f,0.f,0.f};
  f32x4 acc1 = (f32x4){0.f,0.f,0.f,0.f};
  const int wbase = w0 + wv*16;
  const int zoff = 5*W*8;
  #pragma unroll
  for (int ks = 0; ks < 10; ++ks){
    int kh = ks >> 1, kw = (ks & 1)*4 + (lane>>4);
    int col = wbase + (lane&15) + kw;
    int off = (col < W) ? (kh*W + col)*8 : zoff;
    bf16x8 a = *reinterpret_cast<const bf16x8*>(lds + off);
    if (ks & 1) acc1 = __builtin_amdgcn_mfma_f32_16x16x32_bf16(a, bfr[ks], acc1, 0,0,0);
    else        acc0 = __builtin_amdgcn_mfma_f32_16x16x32_bf16(a, bfr[ks], acc0, 0,0,0);
  }

  int n = lane & 15;
  float bv = bz[n];
  #pragma unroll
  for (int ri=0; ri<4; ++ri){
    int w = wbase + (lane>>4)*4 + ri;
    size_t idx = ((size_t)(h*W + w))*16 + n;
    float z = acc0[ri] + acc1[ri] + bv;
    skip[idx] += z;
    float xn = x[idx] + z;
    x[idx]  = xn;
    xb[idx] = (unsigned short)f2bf(xn);
  }
}

// ---------------- cout = dfh_tanh(skip), transposed to [f][ch][t] -----------
__global__ __launch_bounds__(256) void k_dtanh_t(const float* __restrict__ s,
                                                 float* __restrict__ o)
{
  __shared__ float tile[256][17];
  int c = blockIdx.x;
  int tid = threadIdx.x;
  int f = tid & 15, tq = tid >> 4;
  #pragma unroll
  for (int p = 0; p < 16; ++p){
    int t = p*16 + tq;
    tile[t][f] = s[((size_t)t*128 + c)*16 + f];
  }
  __syncthreads();
  int t = tid;
  #pragma unroll
  for (int f2 = 0; f2 < 16; ++f2)
    o[(size_t)f2*32768 + c*256 + t] = dfh_tanh_f(tile[t][f2]);
}

// ---------------- stage C, DFT #1 -------------------------------------------
__global__ __launch_bounds__(256) void k_dft_c1(const float* __restrict__ cout,
                                                float* __restrict__ cft)
{
  __shared__ float ctab[128], stab[128];
  int tid = threadIdx.x;
  if (tid < 128){
    float ang = (float)tid * (6.283185307179586f/128.f);
    ctab[tid] = cosf(ang); stab[tid] = sinf(ang);
  }
  __syncthreads();
  int gid = blockIdx.x*256 + tid;                  // f*32768 + c*256 + t
  int t = gid & 255, c = (gid>>8)&127, f = gid>>15;
  int j = (c + 64) & 127;
  const float* base = cout + (size_t)f*32768 + t;
  float acc = 0.5f*base[0];
  for (int k=1; k<64; ++k){
    float re = base[(2*k)*256], im = base[(2*k+1)*256];
    int m = (j*k) & 127;
    acc += re*ctab[m] + im*stab[m];
  }
  cft[(f*128 + c)*256 + t] = acc;
}

// ---------------- stage C, DFT #2 + hilbert/conj/mask collapse --------------
__global__ __launch_bounds__(256) void k_dft_c2(const float* __restrict__ cft,
                                                const float* __restrict__ times,
                                                float* __restrict__ hinp)
{
  __shared__ float ctab[256], stab[256];
  int tid = threadIdx.x;
  {
    float ang = (float)tid * (6.283185307179586f/256.f);
    ctab[tid] = cosf(ang); stab[tid] = sinf(ang);
  }
  __syncthreads();
  int gid = blockIdx.x*256 + tid;                  // f*16384 + c*128 + k
  int k = gid & 127, c = (gid>>7)&127, f = gid>>14;
  const float* r = cft + (f*128 + c)*256;
  float ar = 0.f, as = 0.f;
  for (int t=0; t<256; ++t){
    float rv = r[t];
    int m = (k*t) & 255;
    ar += rv*ctab[m];
    as += rv*stab[m];
  }
  float q;
  if (k == 0) q = 1.f/128.f;
  else {
    float mk = (fabsf(times[2*k]) > 0.f) ? 1.f : 0.f;
    q = ((k & 1) ? -1.f : 1.f) * (1.f/128.f) * mk;
  }
  float* o = hinp + (c*256 + 2*k)*16 + f;
  o[0]  = q*ar;
  o[16] = q*as;
}

// ---------------- hout_cat = [dfh_tanh(skip_h), hinp]; init fnorm bits ------
__global__ __launch_bounds__(256) void k_houtcat(const float* __restrict__ skip,
                                                 const float* __restrict__ hinp,
                                                 float* __restrict__ hc,
                                                 unsigned* __restrict__ fb)
{
  int gid = blockIdx.x*256 + threadIdx.x;          // c*256 + t
  if (gid == 0) *fb = 0u;
  if (gid >= NCC*NTT) return;
  #pragma unroll
  for (int f=0; f<16; ++f){
    hc[gid*32 + f]      = dfh_tanh_f(skip[gid*16+f]);
    hc[gid*32 + 16 + f] = hinp[gid*16+f];
  }
}

// ---------------- stage E DFT + fused fnorm atomicMax ------------------------
__global__ __launch_bounds__(256) void k_dft_e(const float* __restrict__ hc,
                                               float* __restrict__ hft,
                                               unsigned* __restrict__ fb)
{
  __shared__ float ctab[256], stab[256];
  int tid = threadIdx.x;
  {
    float ang = (float)tid * (6.283185307179586f/256.f);
    ctab[tid] = cosf(ang); stab[tid] = sinf(ang);
  }
  __syncthreads();
  int gid = blockIdx.x*256 + tid;                  // c*8192 + t*32 + f
  int f = gid & 31, t = (gid>>5)&255, c = gid>>13;
  int j = (t + 128) & 255;
  const float* base = hc + c*(256*32) + f;
  float acc = 0.5f*base[0];
  for (int k=1; k<128; ++k){
    float re = base[(2*k)*32], im = base[(2*k+1)*32];
    int m = (j*k) & 255;
    acc += re*ctab[m] + im*stab[m];
  }
  hft[(c*256 + t)*32 + f] = acc;
  // fused fnorm: wave max of |acc| -> one atomicMax per wave
  float m = fabsf(acc);
  #pragma unroll
  for (int off=32; off>0; off>>=1) m = fmaxf(m, __shfl_down(m, off));
  if ((tid & 63) == 0) atomicMax(fb, __float_as_uint(m));
}

// ---------------- ref init: tile(hft/fnorm, 2) ------------------------------
__global__ __launch_bounds__(256) void k_refinit(const float* __restrict__ hft,
                                                 const unsigned* __restrict__ fb,
                                                 float* __restrict__ ref)
{
  int gid = blockIdx.x*256 + threadIdx.x;          // ct*64 + f
  if (gid >= NCC*NTT*64) return;
  float fn = __uint_as_float(*fb);
  int f = gid & 63, ct = gid >> 6;
  ref[gid] = hft[ct*32 + (f & 31)] / fn;
}

// ---------------- refine weights -> fragments, ALL 4 steps ------------------
__global__ __launch_bounds__(256) void k_wconv4(
    const float* __restrict__ wt0, const float* __restrict__ wr0,
    unsigned short* __restrict__ bfrag)
{
  int gid = blockIdx.x*256 + threadIdx.x;          // step*41472 + frag*64 + lane
  if (gid >= 4*648*64) return;
  int step = gid / 41472, rem = gid % 41472;
  int lane = rem & 63, frag = rem >> 6;
  int nt = frag & 3, kt = (frag>>2) & 1, p = frag >> 3;
  const float* wt = wt0 + step*165888;
  const float* wr = wr0 + step*165888;
  int o = nt*16 + (lane & 15);
  int ci0 = kt*32 + (lane>>4)*8;
  const float* src = (o < 32) ? (wt + (p*64 + ci0)*32 + o)
                              : (wr + (p*64 + ci0)*32 + (o-32));
  unsigned pk[4];
  #pragma unroll
  for (int j=0;j<4;++j)
    pk[j] = f2bf(src[(2*j)*32]) | (f2bf(src[(2*j+1)*32]) << 16);
  uint4 v; v.x = pk[0]; v.y = pk[1]; v.z = pk[2]; v.w = pk[3];
  *reinterpret_cast<uint4*>(bfrag + (size_t)gid*8) = v;
}

// ---------------- refine staging helpers (reg prefetch, 40-row tile) --------
__device__ __forceinline__ void ref_stage_load2(const float* __restrict__ srcf,
    int c, int kh, int t0, int tid, float4 (&fr)[2][2])
{
  int cc = c + kh - 4;
  #pragma unroll
  for (int r2=0; r2<2; ++r2){
    float4 z = make_float4(0.f,0.f,0.f,0.f);
    fr[r2][0] = z; fr[r2][1] = z;
    int q = tid + r2*256;
    if (q < 320){
      int row = q >> 3, c16 = q & 7;
      int t = t0 - 4 + row;
      if (t >= 0 && t < 256){
        const float* sp = srcf + ((size_t)(cc*256 + t))*64 + c16*8;
        fr[r2][0] = *reinterpret_cast<const float4*>(sp);
        fr[r2][1] = *reinterpret_cast<const float4*>(sp + 4);
      }
    }
  }
}

__device__ __forceinline__ void ref_stage_write2(unsigned short* lds,
    int tid, float4 (&fr)[2][2])
{
  #pragma unroll
  for (int r2=0; r2<2; ++r2){
    int q = tid + r2*256;
    if (q < 320){
      int row = q >> 3, c16 = q & 7;
      uint4 v;
      v.x = f2bf(fr[r2][0].x) | (f2bf(fr[r2][0].y)<<16);
      v.y = f2bf(fr[r2][0].z) | (f2bf(fr[r2][0].w)<<16);
      v.z = f2bf(fr[r2][1].x) | (f2bf(fr[r2][1].y)<<16);
      v.w = f2bf(fr[r2][1].z) | (f2bf(fr[r2][1].w)<<16);
      *reinterpret_cast<uint4*>(&lds[row*64 + ((c16 ^ (row&7))*8)]) = v;
    }
  }
}

// ---------------- refine: fused tt/rr 9x9 conv via MFMA ---------------------
// 1024 blocks = 128 c x 8 t-tiles of 32 (XCD swizzle), 256 threads = 4 waves.
// Wave (mt, kt): mt = M-half (16 rows), kt = K-half (32 ci); kt-partials
// reduced through LDS. R15: kw loop fully unrolled with 1-ahead B-frag
// prefetch (phase was B-load-latency bound: 3.8 kcy/phase vs 180 cy MFMA).
__global__ __launch_bounds__(256) void k_refmfma(
    const float* __restrict__ srcf, float* __restrict__ dstf,
    const unsigned short* __restrict__ bfrag,
    const float* __restrict__ bt, const float* __restrict__ br)
{
  __shared__ __align__(16) unsigned short ldsA[2][40*64];  // 2 x 5 KB
  __shared__ float redbuf[2][16][65];                       // 8.3 KB, padded
  const int tid = threadIdx.x, lane = tid & 63, wv = tid >> 6;
  const int mt = wv & 1, kt = wv >> 1;
  int bid = blockIdx.x;
  int wg = (bid & 7)*128 + (bid >> 3);             // bijective: 1024 % 8 == 0
  const int c  = wg >> 3;
  const int t0 = (wg & 7) * 32;

  f32x4 acc[4];
  #pragma unroll
  for (int nt=0; nt<4; ++nt) acc[nt] = (f32x4){0.f,0.f,0.f,0.f};

  const int kh0 = (c < 4)   ? 4 - c   : 0;
  const int kh1 = (c > 123) ? 131 - c : 8;

  float4 fr[2][2];
  ref_stage_load2(srcf, c, kh0, t0, tid, fr);
  int cur = 0;
  for (int kh = kh0; kh <= kh1; ++kh){
    ref_stage_write2(ldsA[cur], tid, fr);
    __syncthreads();
    if (kh < kh1) ref_stage_load2(srcf, c, kh+1, t0, tid, fr);

    // B-frag software pipeline: load kw's frags one iteration ahead.
    const unsigned short* bb0 = bfrag + (size_t)(kh*9)*4096;
    bf16x8 bcur[4];
    #pragma unroll
    for (int nt=0; nt<4; ++nt)
      bcur[nt] = *reinterpret_cast<const bf16x8*>(bb0 + ((kt*4+nt)*64 + lane)*8);
    #pragma unroll
    for (int kw=0; kw<9; ++kw){
      bf16x8 bnxt[4];
      if (kw < 8){
        const unsigned short* bb = bfrag + (size_t)(kh*9 + kw + 1)*4096;
        #pragma unroll
        for (int nt=0; nt<4; ++nt)
          bnxt[nt] = *reinterpret_cast<const bf16x8*>(bb + ((kt*4+nt)*64 + lane)*8);
      }
      const int j = mt*16 + (lane&15) + kw;        // 0..39
      bf16x8 a = *reinterpret_cast<const bf16x8*>(
          &ldsA[cur][j*64 + (((kt*4 + (lane>>4)) ^ (j&7))*8)]);
      #pragma unroll
      for (int nt=0; nt<4; ++nt)
        acc[nt] = __builtin_amdgcn_mfma_f32_16x16x32_bf16(a, bcur[nt], acc[nt], 0,0,0);
      if (kw < 8){
        #pragma unroll
        for (int nt=0; nt<4; ++nt) bcur[nt] = bnxt[nt];
      }
    }
    __syncthreads();
    cur ^= 1;
  }

  if (kt == 1){
    #pragma unroll
    for (int nt=0; nt<4; ++nt)
      #pragma unroll
      for (int ri=0; ri<4; ++ri)
        redbuf[mt][nt*4+ri][lane] = acc[nt][ri];
  }
  __syncthreads();
  if (kt == 0){
    #pragma unroll
    for (int nt=0; nt<4; ++nt){
      int o = nt*16 + (lane&15);
      float bv = (o < 32) ? bt[o] : br[o-32];
      #pragma unroll
      for (int ri=0; ri<4; ++ri){
        int t = t0 + mt*16 + (lane>>4)*4 + ri;
        float v = acc[nt][ri] + redbuf[mt][nt*4+ri][lane] + bv;
        v = (nt < 2) ? dfh_tanh_f(v) : (v > 0.f ? v : 0.02f*v);
        size_t idx = ((size_t)(c*256 + t))*64 + o;
        dstf[idx] = v + srcf[idx];
      }
    }
  }
}

// ---------------- final dense (96 -> 2), fnorm scaling fused ----------------
__global__ __launch_bounds__(256) void k_final(const float* __restrict__ ref,
                                               const float* __restrict__ hft,
                                               const unsigned* __restrict__ fb,
                                               const float* __restrict__ dw,
                                               const float* __restrict__ db,
                                               float* __restrict__ out)
{
  int gid = blockIdx.x*256 + threadIdx.x;          // c*256 + t
  if (gid >= NCC*NTT) return;
  float fn = __uint_as_float(*fb);
  const float* rp = ref + gid*64;
  const float* hp = hft + gid*32;
  float s0 = db[0], s1 = db[1];
  #pragma unroll 8
  for (int f=0; f<64; ++f){ float v = rp[f]*fn; s0 += v*dw[f*2]; s1 += v*dw[f*2+1]; }
  #pragma unroll 8
  for (int f=0; f<32; ++f){ float v = hp[f]; s0 += v*dw[(64+f)*2]; s1 += v*dw[(64+f)*2+1]; }
  out[gid*2]   = s0;
  out[gid*2+1] = s1/fn;
}

extern "C" void kernel_launch(void* const* d_in, const int* in_sizes, int n_in,
                              void* d_out, int out_size, void* d_ws, size_t ws_size,
                              hipStream_t stream)
{
  const float* times    = (const float*)d_in[0];
  const float* times_in = (const float*)d_in[1];
  const float* i2nc     = (const float*)d_in[2];
  const float* i2c      = (const float*)d_in[3];
  const float* cdw  = (const float*)d_in[4];  const float* cdb  = (const float*)d_in[5];
  const float* cwy1 = (const float*)d_in[6];  const float* cby1 = (const float*)d_in[7];
  const float* cwy2 = (const float*)d_in[8];  const float* cby2 = (const float*)d_in[9];
  const float* cwz0 = (const float*)d_in[10]; const float* cbz0 = (const float*)d_in[11];
  const float* hdw  = (const float*)d_in[12]; const float* hdb  = (const float*)d_in[13];
  const float* hwy1 = (const float*)d_in[14]; const float* hby1 = (const float*)d_in[15];
  const float* hwy2 = (const float*)d_in[16]; const float* hby2 = (const float*)d_in[17];
  const float* hwz0 = (const float*)d_in[18]; const float* hbz0 = (const float*)d_in[19];
  const float* rwr  = (const float*)d_in[20]; const float* rbr  = (const float*)d_in[21];
  const float* rwt  = (const float*)d_in[22]; const float* rbt  = (const float*)d_in[23];
  const float* fdw  = (const float*)d_in[24]; const float* fdb  = (const float*)d_in[25];
  float* out = (float*)d_out;

  // ---- workspace layout (float offsets), aliased by liveness ---------------
  float* ws = (float*)d_ws;
  float* A   = ws;                 // 524288: x_c / cft / skip_h
  float* Bb  = ws + 524288;        // 524288: skip_c / hinp
  float* C   = ws + 1048576;       // 524288: cout / x_h
  unsigned short* xb = (unsigned short*)(ws + 1572864);   // 524288 bf16
  unsigned short* gb = (unsigned short*)(ws + 1835008);   // 262144 bf16
  float* hcat = ws + 1966080;      // 1048576 (dead after dft_e)
  float* hft  = ws + 3014656;      // 1048576 (live til final)
  unsigned short* gfrag  = (unsigned short*)(ws + 4146176); // 921600 bf16
  unsigned short* zfrag  = (unsigned short*)(ws + 4606976); // 460800 bf16
  float* refA = ws;                // [0, 2097152)
  unsigned short* bfrag4 = (unsigned short*)(ws + 2097152); // 1327104 bf16
  float* refB = ws + 4146176;      // [4146176, 6243328) overlays gfrag,zfrag
  unsigned* fb = (unsigned*)(ws + 6243328);
  // total 6,243,329 floats ~= 25.0 MB

  float* x_c = A;  float* skp_c = Bb; float* cout = C;
  float* cft = A;  float* hinp  = Bb; float* x_h  = C; float* skp_h = A;

  static const int DILS[15] = {1,2,3,4,6,8,10,12,14,16,18,20,24,28,32};

  // ---- pack all 90 layers' wave weights into fragment order ----
  k_wpack<<<675,256,0,stream>>>(cwy1, cwy2, cwz0, hwy1, hwy2, hwz0, gfrag, zfrag);

  // ---- c fidnet layer (H=256 t, W=128 c) ----
  k_build_c<<<128,256,0,stream>>>(times, times_in, i2nc, i2c, cdw, cdb, x_c, xb, skp_c);
  for (int i=0; i<45; ++i){
    int dil = DILS[i % 15];
    k_gate_mfma<128><<<256,512,0,stream>>>(xb, gb, gfrag + (size_t)i*10240,
                                           cby1 + i*8, cby2 + i*8, 256, dil);
    k_zres_mfma<128><<<256,512,0,stream>>>(gb, x_c, xb, skp_c, zfrag + (size_t)i*5120,
                                           cbz0 + i*16, 256);
  }
  k_dtanh_t<<<128,256,0,stream>>>(skp_c, cout);

  // ---- spectral block ----
  k_dft_c1<<<2048,256,0,stream>>>(cout, cft);
  k_dft_c2<<<1024,256,0,stream>>>(cft, times, hinp);

  // ---- h fidnet layer (H=128 c, W=256 t) ----
  k_build_h<<<128,256,0,stream>>>(hinp, hdw, hdb, x_h, xb, skp_h);
  for (int i=0; i<45; ++i){
    int dil = DILS[i % 15];
    k_gate_mfma<256><<<256,512,0,stream>>>(xb, gb, gfrag + (size_t)(45+i)*10240,
                                           hby1 + i*8, hby2 + i*8, 128, dil);
    k_zres_mfma<256><<<256,512,0,stream>>>(gb, x_h, xb, skp_h, zfrag + (size_t)(45+i)*5120,
                                           hbz0 + i*16, 128);
  }
  k_houtcat<<<128,256,0,stream>>>(skp_h, hinp, hcat, fb);

  // ---- stage E DFT (+fused fnorm) ----
  k_dft_e<<<4096,256,0,stream>>>(hcat, hft, fb);

  // ---- refine: pack all 4 steps once, then 4 MFMA convs ----
  k_wconv4<<<648,256,0,stream>>>(rwt, rwr, bfrag4);
  k_refinit<<<8192,256,0,stream>>>(hft, fb, refA);
  float* rsrc = refA; float* rdst = refB;
  for (int i=0; i<4; ++i){
    k_refmfma<<<1024,256,0,stream>>>(rsrc, rdst, bfrag4 + (size_t)i*331776,
                                     rbt + i*32, rbr + i*32);
    float* tmp = rsrc; rsrc = rdst; rdst = tmp;
  }

  // ---- final dense ----
  k_final<<<128,256,0,stream>>>(rsrc, hft, fb, fdw, fdb, out);
}

// Round 16
// 1243.187 us; speedup vs baseline: 1.1261x; 1.1261x over previous
//
#include <hip/hip_runtime.h>

#define NTT 256
#define NCC 128

typedef __attribute__((ext_vector_type(8))) short bf16x8;
typedef __attribute__((ext_vector_type(4))) float f32x4;

__device__ __forceinline__ float dfh_tanh_f(float v){ return tanhf(v)*0.98f + 0.02f*v; }
__device__ __forceinline__ float dfh_sig_f(float v){ return 0.98f/(1.f+expf(-v)) + 0.02f*v; }
__device__ __forceinline__ unsigned f2bf(float x){
  unsigned u = __float_as_uint(x);
  return (u + 0x7fffu + ((u>>16)&1u)) >> 16;
}

// ---------------- build c-layer input + dense + tanh; zero skip -------------
__global__ __launch_bounds__(256) void k_build_c(
    const float* __restrict__ times, const float* __restrict__ times_in,
    const float* __restrict__ i2nc, const float* __restrict__ i2c,
    const float* __restrict__ dw, const float* __restrict__ db,
    float* __restrict__ x, unsigned short* __restrict__ xb,
    float* __restrict__ skip)
{
  int gid = blockIdx.x*256 + threadIdx.x;          // t*128 + c
  if (gid >= NTT*NCC) return;
  int c = gid & 127, t = gid >> 7;
  float v0 = i2nc[c*NTT + t];
  float v1 = i2c [c*NTT + t];
  float v2 = times[t];
  float v3 = times_in[c];
  #pragma unroll
  for (int f=0; f<16; ++f){
    float a = v0*dw[f] + v1*dw[16+f] + v2*dw[32+f] + v3*dw[48+f] + db[f];
    float xv = dfh_tanh_f(a);
    x[gid*16+f]    = xv;
    xb[gid*16+f]   = (unsigned short)f2bf(xv);
    skip[gid*16+f] = 0.f;
  }
}

// ---------------- h-layer dense + tanh; zero skip ---------------------------
__global__ __launch_bounds__(256) void k_build_h(
    const float* __restrict__ hinp, const float* __restrict__ dw,
    const float* __restrict__ db, float* __restrict__ x,
    unsigned short* __restrict__ xb, float* __restrict__ skip)
{
  int gid = blockIdx.x*256 + threadIdx.x;          // c*256 + t
  if (gid >= NCC*NTT) return;
  const float* in = hinp + gid*16;
  float iv[16];
  #pragma unroll
  for (int i=0;i<16;i++) iv[i]=in[i];
  #pragma unroll
  for (int f=0; f<16; ++f){
    float a = db[f];
    #pragma unroll
    for (int i=0;i<16;i++) a += iv[i]*dw[i*16+f];
    float xv = dfh_tanh_f(a);
    x[gid*16+f]    = xv;
    xb[gid*16+f]   = (unsigned short)f2bf(xv);
    skip[gid*16+f] = 0.f;
  }
}

// ---------------- pack wave-layer weights into MFMA fragment order ----------
__global__ __launch_bounds__(256) void k_wpack(
    const float* __restrict__ cwy1, const float* __restrict__ cwy2,
    const float* __restrict__ cwz0,
    const float* __restrict__ hwy1, const float* __restrict__ hwy2,
    const float* __restrict__ hwz0,
    unsigned short* __restrict__ gfrag, unsigned short* __restrict__ zfrag)
{
  int tid = blockIdx.x*256 + threadIdx.x;
  if (tid < 115200){
    int lane = tid & 63, ks = (tid>>6) % 20, layer = tid / 1280;
    const float* w1 = (layer < 45) ? cwy1 + layer*5120 : hwy1 + (layer-45)*5120;
    const float* w2 = (layer < 45) ? cwy2 + layer*5120 : hwy2 + (layer-45)*5120;
    int n = lane & 15;
    unsigned pk[4];
    #pragma unroll
    for (int jj=0; jj<4; ++jj){
      unsigned hl[2];
      #pragma unroll
      for (int h2=0; h2<2; ++h2){
        int k = ks*32 + (lane>>4)*8 + jj*2 + h2;
        int tap = k>>4, ci = k&15;
        float v = (n<8) ? w1[(tap*16+ci)*8 + n] : w2[(tap*16+ci)*8 + (n-8)];
        hl[h2] = f2bf(v);
      }
      pk[jj] = hl[0] | (hl[1]<<16);
    }
    uint4 v4; v4.x=pk[0]; v4.y=pk[1]; v4.z=pk[2]; v4.w=pk[3];
    *reinterpret_cast<uint4*>(gfrag + (size_t)tid*8) = v4;
  } else if (tid < 172800){
    int t2 = tid - 115200;
    int lane = t2 & 63, ks = (t2>>6) % 10, layer = t2 / 640;
    const float* wz = (layer < 45) ? cwz0 + layer*5120 : hwz0 + (layer-45)*5120;
    int n = lane & 15;
    unsigned pk[4];
    #pragma unroll
    for (int jj=0; jj<4; ++jj){
      unsigned hl[2];
      #pragma unroll
      for (int h2=0; h2<2; ++h2){
        int k = ks*32 + (lane>>4)*8 + jj*2 + h2;
        int tap = k>>3, ci = k&7;
        hl[h2] = f2bf(wz[(tap*8+ci)*16 + n]);
      }
      pk[jj] = hl[0] | (hl[1]<<16);
    }
    uint4 v4; v4.x=pk[0]; v4.y=pk[1]; v4.z=pk[2]; v4.w=pk[3];
    *reinterpret_cast<uint4*>(zfrag + (size_t)t2*8) = v4;
  }
}

// ---------------- gate: g = dfh_tanh(y1)*dfh_sigmoid(y2) via MFMA -----------
// xb: [H][W][16] bf16. grid = H*(W/128), 512 threads. M=128 per block, N=16.
// XCD-chunked row swizzle; B-frags preloaded to regs; dual-accumulator ILP.
template<int W>
__global__ __launch_bounds__(512) void k_gate_mfma(
    const unsigned short* __restrict__ xb, unsigned short* __restrict__ gb,
    const unsigned short* __restrict__ bfrag,
    const float* __restrict__ by1, const float* __restrict__ by2,
    int H, int dil)
{
  __shared__ __align__(16) unsigned short lds[(10*W+1)*8];
  const int tid = threadIdx.x, lane = tid & 63, wv = tid >> 6;
  const int nb = W/128;
  const int bid = blockIdx.x;
  const int wg = (bid & 7) * (gridDim.x >> 3) + (bid >> 3);  // XCD-chunked
  const int h  = wg / nb;
  const int w0 = (wg % nb) * 128;
  const int NE = 10*W;

  bf16x8 bfr[20];                                  // preload B-frags (T14)
  #pragma unroll
  for (int ks = 0; ks < 20; ++ks)
    bfr[ks] = *reinterpret_cast<const bf16x8*>(bfrag + (ks*64 + lane)*8);

  for (int q = tid; q < NE; q += 512){
    int q2 = q >> 1, chunk = q & 1;
    int col = q2 % W, r = q2 / W;
    int hh = h + r - 2;
    uint4 v = make_uint4(0u,0u,0u,0u);
    if (hh >= 0 && hh < H)
      v = *reinterpret_cast<const uint4*>(xb + ((size_t)(hh*W+col))*16 + chunk*8);
    *reinterpret_cast<uint4*>(lds + ((r*2+chunk)*W + col)*8) = v;
  }
  if (tid == 0) *reinterpret_cast<uint4*>(lds + (size_t)NE*8) = make_uint4(0u,0u,0u,0u);
  __syncthreads();

  f32x4 acc0 = (f32x4){0.f,0.f,0.f,0.f};
  f32x4 acc1 = (f32x4){0.f,0.f,0.f,0.f};
  const int wbase = w0 + wv*16;
  const int zoff = NE*8;
  #pragma unroll
  for (int ks = 0; ks < 20; ++ks){
    int kh = ks >> 2, kw0 = (ks & 3)*2;
    if (w0 + dil*kw0 >= W) continue;               // uniform: all-zero step
    int kw = kw0 + (lane>>5);
    int chunk = (lane>>4) & 1;
    int col = wbase + (lane&15) + dil*kw;
    int off = (col < W) ? ((kh*2+chunk)*W + col)*8 : zoff;
    bf16x8 a = *reinterpret_cast<const bf16x8*>(lds + off);
    if (ks & 1) acc1 = __builtin_amdgcn_mfma_f32_16x16x32_bf16(a, bfr[ks], acc1, 0,0,0);
    else        acc0 = __builtin_amdgcn_mfma_f32_16x16x32_bf16(a, bfr[ks], acc0, 0,0,0);
  }

  int n = lane & 15;
  float b1 = by1[n & 7], b2 = by2[n & 7];
  #pragma unroll
  for (int ri=0; ri<4; ++ri){
    float av = acc0[ri] + acc1[ri];
    float own = av + b1;
    float oth = __shfl_xor(av, 8) + b2;
    if (n < 8){
      float gv = dfh_tanh_f(own) * dfh_sig_f(oth);
      int w = wbase + (lane>>4)*4 + ri;
      gb[((size_t)(h*W + w))*8 + n] = (unsigned short)f2bf(gv);
    }
  }
}

// ---------------- zres: z-conv via MFMA + skip/x residual + bf16 mirror -----
template<int W>
__global__ __launch_bounds__(512) void k_zres_mfma(
    const unsigned short* __restrict__ gb,
    float* __restrict__ x, unsigned short* __restrict__ xb,
    float* __restrict__ skip,
    const unsigned short* __restrict__ bfrag,
    const float* __restrict__ bz, int H)
{
  __shared__ __align__(16) unsigned short lds[(5*W+1)*8];
  const int tid = threadIdx.x, lane = tid & 63, wv = tid >> 6;
  const int nb = W/128;
  const int bid = blockIdx.x;
  const int wg = (bid & 7) * (gridDim.x >> 3) + (bid >> 3);  // XCD-chunked
  const int h  = wg / nb;
  const int w0 = (wg % nb) * 128;

  bf16x8 bfr[10];                                  // preload B-frags
  #pragma unroll
  for (int ks = 0; ks < 10; ++ks)
    bfr[ks] = *reinterpret_cast<const bf16x8*>(bfrag + (ks*64 + lane)*8);

  for (int q = tid; q < 5*W; q += 512){
    int col = q % W, r = q / W;
    int hh = h + r - 2;
    uint4 v = make_uint4(0u,0u,0u,0u);
    if (hh >= 0 && hh < H)
      v = *reinterpret_cast<const uint4*>(gb + ((size_t)(hh*W+col))*8);
    *reinterpret_cast<uint4*>(lds + (r*W+col)*8) = v;
  }
  if (tid == 0) *reinterpret_cast<uint4*>(lds + (size_t)(5*W)*8) = make_uint4(0u,0u,0u,0u);
  __syncthreads();

  f32x4 acc0 = (f32x4){0.f,0.f,0.f,0.f};
  f32x4 acc1 = (f32x4){0.f,0.f,0.f,0.f};
  const int wbase = w0 + wv*16;
  const int zoff = 5*W*8;
  #pragma unroll
  for (int ks = 0; ks < 10; ++ks){
    int kh = ks >> 1, kw = (ks & 1)*4 + (lane>>4);
    int col = wbase + (lane&15) + kw;
    int off = (col < W) ? (kh*W + col)*8 : zoff;
    bf16x8 a = *reinterpret_cast<const bf16x8*>(lds + off);
    if (ks & 1) acc1 = __builtin_amdgcn_mfma_f32_16x16x32_bf16(a, bfr[ks], acc1, 0,0,0);
    else        acc0 = __builtin_amdgcn_mfma_f32_16x16x32_bf16(a, bfr[ks], acc0, 0,0,0);
  }

  int n = lane & 15;
  float bv = bz[n];
  #pragma unroll
  for (int ri=0; ri<4; ++ri){
    int w = wbase + (lane>>4)*4 + ri;
    size_t idx = ((size_t)(h*W + w))*16 + n;
    float z = acc0[ri] + acc1[ri] + bv;
    skip[idx] += z;
    float xn = x[idx] + z;
    x[idx]  = xn;
    xb[idx] = (unsigned short)f2bf(xn);
  }
}

// ---------------- cout = dfh_tanh(skip), transposed to [f][ch][t] -----------
__global__ __launch_bounds__(256) void k_dtanh_t(const float* __restrict__ s,
                                                 float* __restrict__ o)
{
  __shared__ float tile[256][17];
  int c = blockIdx.x;
  int tid = threadIdx.x;
  int f = tid & 15, tq = tid >> 4;
  #pragma unroll
  for (int p = 0; p < 16; ++p){
    int t = p*16 + tq;
    tile[t][f] = s[((size_t)t*128 + c)*16 + f];
  }
  __syncthreads();
  int t = tid;
  #pragma unroll
  for (int f2 = 0; f2 < 16; ++f2)
    o[(size_t)f2*32768 + c*256 + t] = dfh_tanh_f(tile[t][f2]);
}

// ---------------- stage C, DFT #1 -------------------------------------------
__global__ __launch_bounds__(256) void k_dft_c1(const float* __restrict__ cout,
                                                float* __restrict__ cft)
{
  __shared__ float ctab[128], stab[128];
  int tid = threadIdx.x;
  if (tid < 128){
    float ang = (float)tid * (6.283185307179586f/128.f);
    ctab[tid] = cosf(ang); stab[tid] = sinf(ang);
  }
  __syncthreads();
  int gid = blockIdx.x*256 + tid;                  // f*32768 + c*256 + t
  int t = gid & 255, c = (gid>>8)&127, f = gid>>15;
  int j = (c + 64) & 127;
  const float* base = cout + (size_t)f*32768 + t;
  float acc = 0.5f*base[0];
  for (int k=1; k<64; ++k){
    float re = base[(2*k)*256], im = base[(2*k+1)*256];
    int m = (j*k) & 127;
    acc += re*ctab[m] + im*stab[m];
  }
  cft[(f*128 + c)*256 + t] = acc;
}

// ---------------- stage C, DFT #2 + hilbert/conj/mask collapse --------------
__global__ __launch_bounds__(256) void k_dft_c2(const float* __restrict__ cft,
                                                const float* __restrict__ times,
                                                float* __restrict__ hinp)
{
  __shared__ float ctab[256], stab[256];
  int tid = threadIdx.x;
  {
    float ang = (float)tid * (6.283185307179586f/256.f);
    ctab[tid] = cosf(ang); stab[tid] = sinf(ang);
  }
  __syncthreads();
  int gid = blockIdx.x*256 + tid;                  // f*16384 + c*128 + k
  int k = gid & 127, c = (gid>>7)&127, f = gid>>14;
  const float* r = cft + (f*128 + c)*256;
  float ar = 0.f, as = 0.f;
  for (int t=0; t<256; ++t){
    float rv = r[t];
    int m = (k*t) & 255;
    ar += rv*ctab[m];
    as += rv*stab[m];
  }
  float q;
  if (k == 0) q = 1.f/128.f;
  else {
    float mk = (fabsf(times[2*k]) > 0.f) ? 1.f : 0.f;
    q = ((k & 1) ? -1.f : 1.f) * (1.f/128.f) * mk;
  }
  float* o = hinp + (c*256 + 2*k)*16 + f;
  o[0]  = q*ar;
  o[16] = q*as;
}

// ---------------- hout_cat = [dfh_tanh(skip_h), hinp]; init fnorm bits ------
__global__ __launch_bounds__(256) void k_houtcat(const float* __restrict__ skip,
                                                 const float* __restrict__ hinp,
                                                 float* __restrict__ hc,
                                                 unsigned* __restrict__ fb)
{
  int gid = blockIdx.x*256 + threadIdx.x;          // c*256 + t
  if (gid == 0) *fb = 0u;
  if (gid >= NCC*NTT) return;
  #pragma unroll
  for (int f=0; f<16; ++f){
    hc[gid*32 + f]      = dfh_tanh_f(skip[gid*16+f]);
    hc[gid*32 + 16 + f] = hinp[gid*16+f];
  }
}

// ---------------- stage E DFT ------------------------------------------------
__global__ __launch_bounds__(256) void k_dft_e(const float* __restrict__ hc,
                                               float* __restrict__ hft)
{
  __shared__ float ctab[256], stab[256];
  int tid = threadIdx.x;
  {
    float ang = (float)tid * (6.283185307179586f/256.f);
    ctab[tid] = cosf(ang); stab[tid] = sinf(ang);
  }
  __syncthreads();
  int gid = blockIdx.x*256 + tid;                  // c*8192 + t*32 + f
  int f = gid & 31, t = (gid>>5)&255, c = gid>>13;
  int j = (t + 128) & 255;
  const float* base = hc + c*(256*32) + f;
  float acc = 0.5f*base[0];
  for (int k=1; k<128; ++k){
    float re = base[(2*k)*32], im = base[(2*k+1)*32];
    int m = (j*k) & 255;
    acc += re*ctab[m] + im*stab[m];
  }
  hft[(c*256 + t)*32 + f] = acc;
}

// ---------------- fnorm = max |hft| : block-reduced, 1 atomic/block ---------
// R16: was 1 atomic/WAVE (4096-16384 same-address device atomics serialize at
// ~10ns each -> 40-160us). Now 256 blocks x 1 atomic = ~3us.
__global__ __launch_bounds__(256) void k_fnorm(const float* __restrict__ hft,
                                               unsigned* __restrict__ fb, int n)
{
  __shared__ float red[4];
  float m = 0.f;
  const float4* p = reinterpret_cast<const float4*>(hft);
  int n4 = n >> 2;
  for (int i = blockIdx.x*256 + threadIdx.x; i < n4; i += gridDim.x*256){
    float4 v = p[i];
    m = fmaxf(m, fmaxf(fmaxf(fabsf(v.x), fabsf(v.y)),
                       fmaxf(fabsf(v.z), fabsf(v.w))));
  }
  #pragma unroll
  for (int off=32; off>0; off>>=1) m = fmaxf(m, __shfl_down(m, off));
  if ((threadIdx.x & 63) == 0) red[threadIdx.x >> 6] = m;
  __syncthreads();
  if (threadIdx.x == 0){
    float mm = fmaxf(fmaxf(red[0], red[1]), fmaxf(red[2], red[3]));
    atomicMax(fb, __float_as_uint(mm));
  }
}

// ---------------- ref init: tile(hft/fnorm, 2) ------------------------------
__global__ __launch_bounds__(256) void k_refinit(const float* __restrict__ hft,
                                                 const unsigned* __restrict__ fb,
                                                 float* __restrict__ ref)
{
  int gid = blockIdx.x*256 + threadIdx.x;          // ct*64 + f
  if (gid >= NCC*NTT*64) return;
  float fn = __uint_as_float(*fb);
  int f = gid & 63, ct = gid >> 6;
  ref[gid] = hft[ct*32 + (f & 31)] / fn;
}

// ---------------- refine weights -> fragments, ALL 4 steps ------------------
__global__ __launch_bounds__(256) void k_wconv4(
    const float* __restrict__ wt0, const float* __restrict__ wr0,
    unsigned short* __restrict__ bfrag)
{
  int gid = blockIdx.x*256 + threadIdx.x;          // step*41472 + frag*64 + lane
  if (gid >= 4*648*64) return;
  int step = gid / 41472, rem = gid % 41472;
  int lane = rem & 63, frag = rem >> 6;
  int nt = frag & 3, kt = (frag>>2) & 1, p = frag >> 3;
  const float* wt = wt0 + step*165888;
  const float* wr = wr0 + step*165888;
  int o = nt*16 + (lane & 15);
  int ci0 = kt*32 + (lane>>4)*8;
  const float* src = (o < 32) ? (wt + (p*64 + ci0)*32 + o)
                              : (wr + (p*64 + ci0)*32 + (o-32));
  unsigned pk[4];
  #pragma unroll
  for (int j=0;j<4;++j)
    pk[j] = f2bf(src[(2*j)*32]) | (f2bf(src[(2*j+1)*32]) << 16);
  uint4 v; v.x = pk[0]; v.y = pk[1]; v.z = pk[2]; v.w = pk[3];
  *reinterpret_cast<uint4*>(bfrag + (size_t)gid*8) = v;
}

// ---------------- refine staging helpers (reg prefetch, 40-row tile) --------
__device__ __forceinline__ void ref_stage_load2(const float* __restrict__ srcf,
    int c, int kh, int t0, int tid, float4 (&fr)[2][2])
{
  int cc = c + kh - 4;
  #pragma unroll
  for (int r2=0; r2<2; ++r2){
    float4 z = make_float4(0.f,0.f,0.f,0.f);
    fr[r2][0] = z; fr[r2][1] = z;
    int q = tid + r2*256;
    if (q < 320){
      int row = q >> 3, c16 = q & 7;
      int t = t0 - 4 + row;
      if (t >= 0 && t < 256){
        const float* sp = srcf + ((size_t)(cc*256 + t))*64 + c16*8;
        fr[r2][0] = *reinterpret_cast<const float4*>(sp);
        fr[r2][1] = *reinterpret_cast<const float4*>(sp + 4);
      }
    }
  }
}

__device__ __forceinline__ void ref_stage_write2(unsigned short* lds,
    int tid, float4 (&fr)[2][2])
{
  #pragma unroll
  for (int r2=0; r2<2; ++r2){
    int q = tid + r2*256;
    if (q < 320){
      int row = q >> 3, c16 = q & 7;
      uint4 v;
      v.x = f2bf(fr[r2][0].x) | (f2bf(fr[r2][0].y)<<16);
      v.y = f2bf(fr[r2][0].z) | (f2bf(fr[r2][0].w)<<16);
      v.z = f2bf(fr[r2][1].x) | (f2bf(fr[r2][1].y)<<16);
      v.w = f2bf(fr[r2][1].z) | (f2bf(fr[r2][1].w)<<16);
      *reinterpret_cast<uint4*>(&lds[row*64 + ((c16 ^ (row&7))*8)]) = v;
    }
  }
}

// ---------------- refine: fused tt/rr 9x9 conv via MFMA ---------------------
// 1024 blocks = 128 c x 8 t-tiles of 32 (XCD swizzle), 256 threads = 4 waves.
// Wave (mt, kt): mt = M-half (16 rows), kt = K-half (32 ci); kt-partials
// reduced through LDS (padded scalar layout -> conflict-free).
__global__ __launch_bounds__(256) void k_refmfma(
    const float* __restrict__ srcf, float* __restrict__ dstf,
    const unsigned short* __restrict__ bfrag,
    const float* __restrict__ bt, const float* __restrict__ br)
{
  __shared__ __align__(16) unsigned short ldsA[2][40*64];  // 2 x 5 KB
  __shared__ float redbuf[2][16][65];                       // 8.3 KB, padded
  const int tid = threadIdx.x, lane = tid & 63, wv = tid >> 6;
  const int mt = wv & 1, kt = wv >> 1;
  int bid = blockIdx.x;
  int wg = (bid & 7)*128 + (bid >> 3);             // bijective: 1024 % 8 == 0
  const int c  = wg >> 3;
  const int t0 = (wg & 7) * 32;

  f32x4 acc[4];
  #pragma unroll
  for (int nt=0; nt<4; ++nt) acc[nt] = (f32x4){0.f,0.f,0.f,0.f};

  const int kh0 = (c < 4)   ? 4 - c   : 0;
  const int kh1 = (c > 123) ? 131 - c : 8;

  float4 fr[2][2];
  ref_stage_load2(srcf, c, kh0, t0, tid, fr);
  int cur = 0;
  for (int kh = kh0; kh <= kh1; ++kh){
    ref_stage_write2(ldsA[cur], tid, fr);
    __syncthreads();
    if (kh < kh1) ref_stage_load2(srcf, c, kh+1, t0, tid, fr);
    for (int kw=0; kw<9; ++kw){
      const int p = kh*9 + kw;
      const unsigned short* bb = bfrag + (size_t)p*4096;
      bf16x8 b[4];
      #pragma unroll
      for (int nt=0; nt<4; ++nt)
        b[nt] = *reinterpret_cast<const bf16x8*>(bb + ((kt*4+nt)*64 + lane)*8);
      const int j = mt*16 + (lane&15) + kw;        // 0..39
      bf16x8 a = *reinterpret_cast<const bf16x8*>(
          &ldsA[cur][j*64 + (((kt*4 + (lane>>4)) ^ (j&7))*8)]);
      #pragma unroll
      for (int nt=0; nt<4; ++nt)
        acc[nt] = __builtin_amdgcn_mfma_f32_16x16x32_bf16(a, b[nt], acc[nt], 0,0,0);
    }
    __syncthreads();
    cur ^= 1;
  }

  if (kt == 1){
    #pragma unroll
    for (int nt=0; nt<4; ++nt)
      #pragma unroll
      for (int ri=0; ri<4; ++ri)
        redbuf[mt][nt*4+ri][lane] = acc[nt][ri];
  }
  __syncthreads();
  if (kt == 0){
    #pragma unroll
    for (int nt=0; nt<4; ++nt){
      int o = nt*16 + (lane&15);
      float bv = (o < 32) ? bt[o] : br[o-32];
      #pragma unroll
      for (int ri=0; ri<4; ++ri){
        int t = t0 + mt*16 + (lane>>4)*4 + ri;
        float v = acc[nt][ri] + redbuf[mt][nt*4+ri][lane] + bv;
        v = (nt < 2) ? dfh_tanh_f(v) : (v > 0.f ? v : 0.02f*v);
        size_t idx = ((size_t)(c*256 + t))*64 + o;
        dstf[idx] = v + srcf[idx];
      }
    }
  }
}

// ---------------- final dense (96 -> 2), fnorm scaling fused ----------------
__global__ __launch_bounds__(256) void k_final(const float* __restrict__ ref,
                                               const float* __restrict__ hft,
                                               const unsigned* __restrict__ fb,
                                               const float* __restrict__ dw,
                                               const float* __restrict__ db,
                                               float* __restrict__ out)
{
  int gid = blockIdx.x*256 + threadIdx.x;          // c*256 + t
  if (gid >= NCC*NTT) return;
  float fn = __uint_as_float(*fb);
  const float* rp = ref + gid*64;
  const float* hp = hft + gid*32;
  float s0 = db[0], s1 = db[1];
  #pragma unroll 8
  for (int f=0; f<64; ++f){ float v = rp[f]*fn; s0 += v*dw[f*2]; s1 += v*dw[f*2+1]; }
  #pragma unroll 8
  for (int f=0; f<32; ++f){ float v = hp[f]; s0 += v*dw[(64+f)*2]; s1 += v*dw[(64+f)*2+1]; }
  out[gid*2]   = s0;
  out[gid*2+1] = s1/fn;
}

extern "C" void kernel_launch(void* const* d_in, const int* in_sizes, int n_in,
                              void* d_out, int out_size, void* d_ws, size_t ws_size,
                              hipStream_t stream)
{
  const float* times    = (const float*)d_in[0];
  const float* times_in = (const float*)d_in[1];
  const float* i2nc     = (const float*)d_in[2];
  const float* i2c      = (const float*)d_in[3];
  const float* cdw  = (const float*)d_in[4];  const float* cdb  = (const float*)d_in[5];
  const float* cwy1 = (const float*)d_in[6];  const float* cby1 = (const float*)d_in[7];
  const float* cwy2 = (const float*)d_in[8];  const float* cby2 = (const float*)d_in[9];
  const float* cwz0 = (const float*)d_in[10]; const float* cbz0 = (const float*)d_in[11];
  const float* hdw  = (const float*)d_in[12]; const float* hdb  = (const float*)d_in[13];
  const float* hwy1 = (const float*)d_in[14]; const float* hby1 = (const float*)d_in[15];
  const float* hwy2 = (const float*)d_in[16]; const float* hby2 = (const float*)d_in[17];
  const float* hwz0 = (const float*)d_in[18]; const float* hbz0 = (const float*)d_in[19];
  const float* rwr  = (const float*)d_in[20]; const float* rbr  = (const float*)d_in[21];
  const float* rwt  = (const float*)d_in[22]; const float* rbt  = (const float*)d_in[23];
  const float* fdw  = (const float*)d_in[24]; const float* fdb  = (const float*)d_in[25];
  float* out = (float*)d_out;

  // ---- workspace layout (float offsets), aliased by liveness ---------------
  float* ws = (float*)d_ws;
  float* A   = ws;                 // 524288: x_c / cft / skip_h
  float* Bb  = ws + 524288;        // 524288: skip_c / hinp
  float* C   = ws + 1048576;       // 524288: cout / x_h
  unsigned short* xb = (unsigned short*)(ws + 1572864);   // 524288 bf16
  unsigned short* gb = (unsigned short*)(ws + 1835008);   // 262144 bf16
  float* hcat = ws + 1966080;      // 1048576 (dead after dft_e)
  float* hft  = ws + 3014656;      // 1048576 (live til final)
  unsigned short* gfrag  = (unsigned short*)(ws + 4146176); // 921600 bf16
  unsigned short* zfrag  = (unsigned short*)(ws + 4606976); // 460800 bf16
  float* refA = ws;                // [0, 2097152)
  unsigned short* bfrag4 = (unsigned short*)(ws + 2097152); // 1327104 bf16
  float* refB = ws + 4146176;      // [4146176, 6243328) overlays gfrag,zfrag
  unsigned* fb = (unsigned*)(ws + 6243328);
  // total 6,243,329 floats ~= 25.0 MB

  float* x_c = A;  float* skp_c = Bb; float* cout = C;
  float* cft = A;  float* hinp  = Bb; float* x_h  = C; float* skp_h = A;

  static const int DILS[15] = {1,2,3,4,6,8,10,12,14,16,18,20,24,28,32};

  // ---- pack all 90 layers' wave weights into fragment order ----
  k_wpack<<<675,256,0,stream>>>(cwy1, cwy2, cwz0, hwy1, hwy2, hwz0, gfrag, zfrag);

  // ---- c fidnet layer (H=256 t, W=128 c) ----
  k_build_c<<<128,256,0,stream>>>(times, times_in, i2nc, i2c, cdw, cdb, x_c, xb, skp_c);
  for (int i=0; i<45; ++i){
    int dil = DILS[i % 15];
    k_gate_mfma<128><<<256,512,0,stream>>>(xb, gb, gfrag + (size_t)i*10240,
                                           cby1 + i*8, cby2 + i*8, 256, dil);
    k_zres_mfma<128><<<256,512,0,stream>>>(gb, x_c, xb, skp_c, zfrag + (size_t)i*5120,
                                           cbz0 + i*16, 256);
  }
  k_dtanh_t<<<128,256,0,stream>>>(skp_c, cout);

  // ---- spectral block ----
  k_dft_c1<<<2048,256,0,stream>>>(cout, cft);
  k_dft_c2<<<1024,256,0,stream>>>(cft, times, hinp);

  // ---- h fidnet layer (H=128 c, W=256 t) ----
  k_build_h<<<128,256,0,stream>>>(hinp, hdw, hdb, x_h, xb, skp_h);
  for (int i=0; i<45; ++i){
    int dil = DILS[i % 15];
    k_gate_mfma<256><<<256,512,0,stream>>>(xb, gb, gfrag + (size_t)(45+i)*10240,
                                           hby1 + i*8, hby2 + i*8, 128, dil);
    k_zres_mfma<256><<<256,512,0,stream>>>(gb, x_h, xb, skp_h, zfrag + (size_t)(45+i)*5120,
                                           hbz0 + i*16, 128);
  }
  k_houtcat<<<128,256,0,stream>>>(skp_h, hinp, hcat, fb);

  // ---- stage E DFT + fnorm (block-reduced) ----
  k_dft_e<<<4096,256,0,stream>>>(hcat, hft);
  k_fnorm<<<256,256,0,stream>>>(hft, fb, 1048576);

  // ---- refine: pack all 4 steps once, then 4 MFMA convs ----
  k_wconv4<<<648,256,0,stream>>>(rwt, rwr, bfrag4);
  k_refinit<<<8192,256,0,stream>>>(hft, fb, refA);
  float* rsrc = refA; float* rdst = refB;
  for (int i=0; i<4; ++i){
    k_refmfma<<<1024,256,0,stream>>>(rsrc, rdst, bfrag4 + (size_t)i*331776,
                                     rbt + i*32, rbr + i*32);
    float* tmp = rsrc; rsrc = rdst; rdst = tmp;
  }

  // ---- final dense ----
  k_final<<<128,256,0,stream>>>(rsrc, hft, fb, fdw, fdb, out);
}